// Round 1
// baseline (564.110 us; speedup 1.0000x reference)
//
#include <hip/hip_runtime.h>

#define D_IN   2304
#define D_SAE  2048
#define TL     24          // T*L
#define BATCH  32
#define K_TOP  128
#define NLAT   (TL * D_SAE)   // 49152
#define KSPLIT 4
#define KS     (D_IN / KSPLIT) // 576
#define BN     256

// ---------------- encode: per-(tl, ntile, ksplit) partial GEMM ----------------
// grid (D_SAE/BN, TL, KSPLIT), block 256. Thread owns one SAE column, acc over 32 batches.
__global__ __launch_bounds__(256) void enc_kernel(const float* __restrict__ x,
                                                  const float* __restrict__ W,
                                                  float* __restrict__ part) {
    const int c  = threadIdx.x;
    const int tl = blockIdx.y;
    const int ks = blockIdx.z;
    const float* Wp = W + ((size_t)(tl * D_IN + ks * KS)) * D_SAE + blockIdx.x * BN + c;
    const float* xp = x + tl * D_IN + ks * KS;   // + b*(TL*D_IN) + k  (wave-uniform)

    float acc[BATCH];
#pragma unroll
    for (int b = 0; b < BATCH; b++) acc[b] = 0.f;

    for (int k0 = 0; k0 < KS; k0 += 8) {
        float w[8];
#pragma unroll
        for (int j = 0; j < 8; j++) w[j] = Wp[(size_t)(k0 + j) * D_SAE];
#pragma unroll
        for (int b = 0; b < BATCH; b++) {
#pragma unroll
            for (int j = 0; j < 8; j++)
                acc[b] = fmaf(xp[b * (TL * D_IN) + k0 + j], w[j], acc[b]);
        }
    }
    float* pp = part + ((size_t)ks * BATCH) * NLAT
                     + (size_t)tl * D_SAE + blockIdx.x * BN + c;
#pragma unroll
    for (int b = 0; b < BATCH; b++) pp[(size_t)b * NLAT] = acc[b];
}

// ---------------- reduce partials + bias -> pre ----------------
__global__ void reduce_kernel(const float* __restrict__ part,
                              const float* __restrict__ b_enc,
                              float* __restrict__ pre) {
    int i = blockIdx.x * blockDim.x + threadIdx.x;   // [0, BATCH*NLAT)
    const size_t S = (size_t)BATCH * NLAT;
    float v = part[i] + part[i + S] + part[i + 2 * S] + part[i + 3 * S];
    pre[i] = v + b_enc[i & (D_SAE - 1)];   // NLAT multiple of 2048 -> i%2048 == s
}

// ---------------- exact top-K per batch row ----------------
#define NBIN 8192
#define CAP  2048
__global__ __launch_bounds__(256) void topk_kernel(const float* __restrict__ pre,
                                                   int* __restrict__ sel_idx,
                                                   float* __restrict__ sel_val,
                                                   int* __restrict__ sel_cnt) {
    const int b   = blockIdx.x;
    const int tid = threadIdx.x;
    __shared__ unsigned hist[NBIN];
    __shared__ unsigned cand_key[CAP];
    __shared__ int      cand_idx[CAP];
    __shared__ unsigned tsum[256];
    __shared__ unsigned suf[256];
    __shared__ int s_T, s_hi, s_ccnt;

    const float* row = pre + (size_t)b * NLAT;
    for (int i = tid; i < NBIN; i += 256) hist[i] = 0;
    if (tid == 0) s_ccnt = 0;
    __syncthreads();

    for (int i = tid; i < NLAT; i += 256) {
        unsigned u   = __float_as_uint(row[i]);
        unsigned key = u ^ ((u >> 31) ? 0xFFFFFFFFu : 0x80000000u); // monotone ascending
        atomicAdd(&hist[key >> 19], 1u);
    }
    __syncthreads();

    unsigned local = 0;
    const int base = tid * (NBIN / 256);
    for (int j = 0; j < NBIN / 256; j++) local += hist[base + j];
    tsum[tid] = local;
    __syncthreads();
    if (tid == 0) {                 // suffix-exclusive sums over 256 thread ranges
        unsigned run = 0;
        for (int t = 255; t >= 0; t--) { suf[t] = run; run += tsum[t]; }
    }
    __syncthreads();
    if (suf[tid] < K_TOP && suf[tid] + tsum[tid] >= K_TOP) {  // exactly one thread
        unsigned c = suf[tid];
        for (int j = NBIN / 256 - 1; j >= 0; j--) {
            int bin = base + j;
            if (c + hist[bin] >= K_TOP) { s_T = bin; s_hi = (int)c; break; }
            c += hist[bin];
        }
    }
    __syncthreads();

    const int T = s_T;
    for (int i = tid; i < NLAT; i += 256) {
        float v      = row[i];
        unsigned u   = __float_as_uint(v);
        unsigned key = u ^ ((u >> 31) ? 0xFFFFFFFFu : 0x80000000u);
        int bin = (int)(key >> 19);
        if (bin > T) {
            int p = atomicAdd(&sel_cnt[b], 1);
            sel_idx[b * K_TOP + p] = i;
            sel_val[b * K_TOP + p] = fmaxf(v, 0.f);
        } else if (bin == T) {
            int p = atomicAdd(&s_ccnt, 1);
            if (p < CAP) { cand_key[p] = key; cand_idx[p] = i; }
        }
    }
    __syncthreads();

    const int need = K_TOP - s_hi;
    const int nc   = min(s_ccnt, CAP);
    for (int c = tid; c < nc; c += 256) {
        unsigned kc = cand_key[c]; int ic = cand_idx[c];
        int rank = 0;
        for (int j = 0; j < nc; j++) {
            unsigned kj = cand_key[j]; int ij = cand_idx[j];
            rank += (kj > kc) || (kj == kc && ij < ic);   // ties -> lower index wins
        }
        if (rank < need) {
            int p = atomicAdd(&sel_cnt[b], 1);
            sel_idx[b * K_TOP + p] = ic;
            sel_val[b * K_TOP + p] = fmaxf(row[ic], 0.f);
        }
    }
}

// ---------------- scatter z ----------------
__global__ void scatter_kernel(const int* __restrict__ sel_idx,
                               const float* __restrict__ sel_val,
                               float* __restrict__ z) {
    int b = blockIdx.x, j = threadIdx.x;   // 128 threads
    z[(size_t)b * NLAT + sel_idx[b * K_TOP + j]] = sel_val[b * K_TOP + j];
}

// ---------------- sparse decode + x_hat + loss ----------------
__global__ __launch_bounds__(256) void dec_kernel(const float* __restrict__ Wd,
                                                  const float* __restrict__ b_dec,
                                                  const float* __restrict__ x,
                                                  const int* __restrict__ sel_idx,
                                                  const float* __restrict__ sel_val,
                                                  float* __restrict__ xhat,
                                                  float* __restrict__ loss) {
    const int tl = blockIdx.x, b = blockIdx.y, tid = threadIdx.x;
    float acc[9];
#pragma unroll
    for (int r = 0; r < 9; r++) acc[r] = b_dec[tl * D_IN + tid + r * 256];

    __shared__ int   s_idx[K_TOP];
    __shared__ float s_val[K_TOP];
    if (tid < K_TOP) { s_idx[tid] = sel_idx[b * K_TOP + tid];
                       s_val[tid] = sel_val[b * K_TOP + tid]; }
    __syncthreads();

    for (int j = 0; j < K_TOP; j++) {
        int f = s_idx[j];
        if ((f >> 11) == tl) {                 // D_SAE = 2048
            float v = s_val[j];
            const float* wrow = Wd + (size_t)f * D_IN;  // (tl*2048+s)*2304
#pragma unroll
            for (int r = 0; r < 9; r++)
                acc[r] = fmaf(v, wrow[tid + r * 256], acc[r]);
        }
    }

    const float* xr = x    + ((size_t)b * TL + tl) * D_IN;
    float*       xo = xhat + ((size_t)b * TL + tl) * D_IN;
    float lsum = 0.f;
#pragma unroll
    for (int r = 0; r < 9; r++) {
        float d = acc[r] - xr[tid + r * 256];
        xo[tid + r * 256] = acc[r];
        lsum += d * d;
    }
    __shared__ float red[256];
    red[tid] = lsum; __syncthreads();
    for (int s = 128; s > 0; s >>= 1) {
        if (tid < s) red[tid] += red[tid + s];
        __syncthreads();
    }
    if (tid == 0) atomicAdd(loss, red[0] * (1.0f / (BATCH * TL)));
}

extern "C" void kernel_launch(void* const* d_in, const int* in_sizes, int n_in,
                              void* d_out, int out_size, void* d_ws, size_t ws_size,
                              hipStream_t stream) {
    const float* x     = (const float*)d_in[0];
    const float* W_enc = (const float*)d_in[1];
    const float* W_dec = (const float*)d_in[2];
    const float* b_enc = (const float*)d_in[3];
    const float* b_dec = (const float*)d_in[4];

    float* out  = (float*)d_out;
    float* loss = out;
    float* xhat = out + 1;
    float* z    = out + 1 + (size_t)BATCH * TL * D_IN;

    float* part    = (float*)d_ws;
    float* pre     = part + (size_t)KSPLIT * BATCH * NLAT;
    int*   sel_idx = (int*)(pre + (size_t)BATCH * NLAT);
    float* sel_val = (float*)(sel_idx + BATCH * K_TOP);
    int*   sel_cnt = (int*)(sel_val + BATCH * K_TOP);

    hipMemsetAsync(loss, 0, sizeof(float), stream);
    hipMemsetAsync(z, 0, (size_t)BATCH * NLAT * sizeof(float), stream);
    hipMemsetAsync(sel_cnt, 0, BATCH * sizeof(int), stream);

    enc_kernel<<<dim3(D_SAE / BN, TL, KSPLIT), 256, 0, stream>>>(x, W_enc, part);
    reduce_kernel<<<(BATCH * NLAT) / 256, 256, 0, stream>>>(part, b_enc, pre);
    topk_kernel<<<BATCH, 256, 0, stream>>>(pre, sel_idx, sel_val, sel_cnt);
    scatter_kernel<<<BATCH, K_TOP, 0, stream>>>(sel_idx, sel_val, z);
    dec_kernel<<<dim3(TL, BATCH), 256, 0, stream>>>(W_dec, b_dec, x, sel_idx, sel_val,
                                                    xhat, loss);
}

// Round 2
// 354.272 us; speedup vs baseline: 1.5923x; 1.5923x over previous
//
#include <hip/hip_runtime.h>

#define D_IN   2304
#define D_SAE  2048
#define TL     24          // T*L
#define BATCH  32
#define K_TOP  128
#define NLAT   (TL * D_SAE)   // 49152
#define NBIN   8192
#define CAP    2048

// ---------------- encode: x staged in LDS, thread owns 2 columns ----------------
// grid (8, TL, KSPLIT), block 128. col = bx*256 + 2*tid. acc[32] batches x 2 cols.
template<int KSPLIT>
__global__ __launch_bounds__(128) void enc_kernel(const float* __restrict__ x,
                                                  const float* __restrict__ W,
                                                  float* __restrict__ part) {
    constexpr int KS  = D_IN / KSPLIT;
    constexpr int BK  = 32;
    constexpr int NCH = KS / BK;
    const int tid = threadIdx.x;
    const int col = blockIdx.x * 256 + 2 * tid;
    const int tl  = blockIdx.y;
    const int ks  = blockIdx.z;

    __shared__ float xs[2][BATCH][BK + 4];   // +4 pad: spread staging writes

    const int brow = tid >> 2, q = tid & 3;  // 32 batch rows x 4 quarters
    const float* xbase = x + ((size_t)(brow * TL + tl)) * D_IN + ks * KS + q * 8;
    const float* Wp    = W + ((size_t)(tl * D_IN + ks * KS)) * D_SAE + col;

    float2 acc[BATCH];
#pragma unroll
    for (int b = 0; b < BATCH; b++) acc[b] = make_float2(0.f, 0.f);

    float4 r0 = *(const float4*)&xbase[0];
    float4 r1 = *(const float4*)&xbase[4];

    for (int ch = 0; ch < NCH; ++ch) {
        const int buf = ch & 1;
        *(float4*)&xs[buf][brow][q * 8]     = r0;
        *(float4*)&xs[buf][brow][q * 8 + 4] = r1;
        __syncthreads();                       // buf ready; prev compute on buf^1 done
        if (ch + 1 < NCH) {                    // prefetch next chunk into regs
            r0 = *(const float4*)&xbase[(ch + 1) * BK];
            r1 = *(const float4*)&xbase[(ch + 1) * BK + 4];
        }
        const float* Wc = Wp + (size_t)(ch * BK) * D_SAE;
#pragma unroll
        for (int k0 = 0; k0 < BK; k0 += 4) {
            float2 w0 = *(const float2*)&Wc[(size_t)(k0    ) * D_SAE];
            float2 w1 = *(const float2*)&Wc[(size_t)(k0 + 1) * D_SAE];
            float2 w2 = *(const float2*)&Wc[(size_t)(k0 + 2) * D_SAE];
            float2 w3 = *(const float2*)&Wc[(size_t)(k0 + 3) * D_SAE];
#pragma unroll
            for (int b = 0; b < BATCH; b++) {
                float4 xv = *(const float4*)&xs[buf][b][k0];   // broadcast read
                acc[b].x = fmaf(xv.x, w0.x, acc[b].x);
                acc[b].y = fmaf(xv.x, w0.y, acc[b].y);
                acc[b].x = fmaf(xv.y, w1.x, acc[b].x);
                acc[b].y = fmaf(xv.y, w1.y, acc[b].y);
                acc[b].x = fmaf(xv.z, w2.x, acc[b].x);
                acc[b].y = fmaf(xv.z, w2.y, acc[b].y);
                acc[b].x = fmaf(xv.w, w3.x, acc[b].x);
                acc[b].y = fmaf(xv.w, w3.y, acc[b].y);
            }
        }
    }
    float* pp = part + (size_t)(ks * BATCH) * NLAT + (size_t)tl * D_SAE + col;
#pragma unroll
    for (int b = 0; b < BATCH; b++)
        *(float2*)&pp[(size_t)b * NLAT] = acc[b];
}

// ---------------- reduce partials + bias -> pre ----------------
template<int KSPLIT>
__global__ void reduce_kernel(const float* __restrict__ part,
                              const float* __restrict__ b_enc,
                              float* __restrict__ pre) {
    int i = blockIdx.x * blockDim.x + threadIdx.x;   // [0, BATCH*NLAT)
    const size_t S = (size_t)BATCH * NLAT;
    float v = 0.f;
#pragma unroll
    for (int s = 0; s < KSPLIT; s++) v += part[i + s * S];
    pre[i] = v + b_enc[i & (D_SAE - 1)];
}

// ---------------- exact top-K per batch row (+ z scatter) ----------------
__global__ __launch_bounds__(256) void topk_kernel(const float* __restrict__ pre,
                                                   int* __restrict__ sel_idx,
                                                   float* __restrict__ sel_val,
                                                   int* __restrict__ sel_cnt,
                                                   float* __restrict__ z) {
    const int b   = blockIdx.x;
    const int tid = threadIdx.x;
    __shared__ unsigned hist[NBIN];
    __shared__ unsigned cand_key[CAP];
    __shared__ int      cand_idx[CAP];
    __shared__ unsigned tsum[256];
    __shared__ unsigned suf[256];
    __shared__ int s_T, s_hi, s_ccnt;

    const float* row = pre + (size_t)b * NLAT;
    float* zrow = z + (size_t)b * NLAT;
    for (int i = tid; i < NBIN; i += 256) hist[i] = 0;
    if (tid == 0) s_ccnt = 0;
    __syncthreads();

    for (int i = tid; i < NLAT; i += 256) {
        unsigned u   = __float_as_uint(row[i]);
        unsigned key = u ^ ((u >> 31) ? 0xFFFFFFFFu : 0x80000000u); // monotone ascending
        atomicAdd(&hist[key >> 19], 1u);
    }
    __syncthreads();

    unsigned local = 0;
    const int base = tid * (NBIN / 256);
    for (int j = 0; j < NBIN / 256; j++) local += hist[base + j];
    tsum[tid] = local;
    __syncthreads();
    if (tid == 0) {                 // suffix-exclusive sums over 256 thread ranges
        unsigned run = 0;
        for (int t = 255; t >= 0; t--) { suf[t] = run; run += tsum[t]; }
    }
    __syncthreads();
    if (suf[tid] < K_TOP && suf[tid] + tsum[tid] >= K_TOP) {  // exactly one thread
        unsigned c = suf[tid];
        for (int j = NBIN / 256 - 1; j >= 0; j--) {
            int bin = base + j;
            if (c + hist[bin] >= K_TOP) { s_T = bin; s_hi = (int)c; break; }
            c += hist[bin];
        }
    }
    __syncthreads();

    const int T = s_T;
    for (int i = tid; i < NLAT; i += 256) {
        float v      = row[i];
        unsigned u   = __float_as_uint(v);
        unsigned key = u ^ ((u >> 31) ? 0xFFFFFFFFu : 0x80000000u);
        int bin = (int)(key >> 19);
        if (bin > T) {
            int p = atomicAdd(&sel_cnt[b], 1);
            sel_idx[b * K_TOP + p] = i;
            sel_val[b * K_TOP + p] = fmaxf(v, 0.f);
            zrow[i] = fmaxf(v, 0.f);
        } else if (bin == T) {
            int p = atomicAdd(&s_ccnt, 1);
            if (p < CAP) { cand_key[p] = key; cand_idx[p] = i; }
        }
    }
    __syncthreads();

    const int need = K_TOP - s_hi;
    const int nc   = min(s_ccnt, CAP);
    for (int c = tid; c < nc; c += 256) {
        unsigned kc = cand_key[c]; int ic = cand_idx[c];
        int rank = 0;
        for (int j = 0; j < nc; j++) {
            unsigned kj = cand_key[j]; int ij = cand_idx[j];
            rank += (kj > kc) || (kj == kc && ij < ic);   // ties -> lower index wins
        }
        if (rank < need) {
            int p = atomicAdd(&sel_cnt[b], 1);
            sel_idx[b * K_TOP + p] = ic;
            sel_val[b * K_TOP + p] = fmaxf(row[ic], 0.f);
            zrow[ic] = fmaxf(row[ic], 0.f);
        }
    }
}

// ---------------- sparse decode + x_hat + loss ----------------
__global__ __launch_bounds__(256) void dec_kernel(const float* __restrict__ Wd,
                                                  const float* __restrict__ b_dec,
                                                  const float* __restrict__ x,
                                                  const int* __restrict__ sel_idx,
                                                  const float* __restrict__ sel_val,
                                                  float* __restrict__ xhat,
                                                  float* __restrict__ loss) {
    const int tl = blockIdx.x, b = blockIdx.y, tid = threadIdx.x;
    float acc[9];
#pragma unroll
    for (int r = 0; r < 9; r++) acc[r] = b_dec[tl * D_IN + tid + r * 256];

    __shared__ int   s_idx[K_TOP];
    __shared__ float s_val[K_TOP];
    if (tid < K_TOP) { s_idx[tid] = sel_idx[b * K_TOP + tid];
                       s_val[tid] = sel_val[b * K_TOP + tid]; }
    __syncthreads();

    for (int j = 0; j < K_TOP; j++) {
        int f = s_idx[j];
        if ((f >> 11) == tl) {                 // D_SAE = 2048
            float v = s_val[j];
            const float* wrow = Wd + (size_t)f * D_IN;
#pragma unroll
            for (int r = 0; r < 9; r++)
                acc[r] = fmaf(v, wrow[tid + r * 256], acc[r]);
        }
    }

    const float* xr = x    + ((size_t)b * TL + tl) * D_IN;
    float*       xo = xhat + ((size_t)b * TL + tl) * D_IN;
    float lsum = 0.f;
#pragma unroll
    for (int r = 0; r < 9; r++) {
        float d = acc[r] - xr[tid + r * 256];
        xo[tid + r * 256] = acc[r];
        lsum += d * d;
    }
    __shared__ float red[256];
    red[tid] = lsum; __syncthreads();
    for (int s = 128; s > 0; s >>= 1) {
        if (tid < s) red[tid] += red[tid + s];
        __syncthreads();
    }
    if (tid == 0) atomicAdd(loss, red[0] * (1.0f / (BATCH * TL)));
}

extern "C" void kernel_launch(void* const* d_in, const int* in_sizes, int n_in,
                              void* d_out, int out_size, void* d_ws, size_t ws_size,
                              hipStream_t stream) {
    const float* x     = (const float*)d_in[0];
    const float* W_enc = (const float*)d_in[1];
    const float* W_dec = (const float*)d_in[2];
    const float* b_enc = (const float*)d_in[3];
    const float* b_dec = (const float*)d_in[4];

    float* out  = (float*)d_out;
    float* loss = out;
    float* xhat = out + 1;
    float* z    = out + 1 + (size_t)BATCH * TL * D_IN;

    const size_t S = (size_t)BATCH * NLAT;              // elements
    const size_t aux = S + BATCH * K_TOP * 2 + BATCH;   // pre + sel arrays
    const bool big = ws_size >= (8 * S + aux + 1024) * sizeof(float);
    const int ksplit = big ? 8 : 4;

    float* part    = (float*)d_ws;
    float* pre     = part + (size_t)ksplit * S;
    int*   sel_idx = (int*)(pre + S);
    float* sel_val = (float*)(sel_idx + BATCH * K_TOP);
    int*   sel_cnt = (int*)(sel_val + BATCH * K_TOP);

    hipMemsetAsync(loss, 0, sizeof(float), stream);
    hipMemsetAsync(z, 0, S * sizeof(float), stream);
    hipMemsetAsync(sel_cnt, 0, BATCH * sizeof(int), stream);

    if (big) {
        enc_kernel<8><<<dim3(8, TL, 8), 128, 0, stream>>>(x, W_enc, part);
        reduce_kernel<8><<<(int)(S / 256), 256, 0, stream>>>(part, b_enc, pre);
    } else {
        enc_kernel<4><<<dim3(8, TL, 4), 128, 0, stream>>>(x, W_enc, part);
        reduce_kernel<4><<<(int)(S / 256), 256, 0, stream>>>(part, b_enc, pre);
    }
    topk_kernel<<<BATCH, 256, 0, stream>>>(pre, sel_idx, sel_val, sel_cnt, z);
    dec_kernel<<<dim3(TL, BATCH), 256, 0, stream>>>(W_dec, b_dec, x, sel_idx, sel_val,
                                                    xhat, loss);
}

// Round 3
// 293.640 us; speedup vs baseline: 1.9211x; 1.2065x over previous
//
#include <hip/hip_runtime.h>

#define D_IN   2304
#define D_SAE  2048
#define TL     24          // T*L
#define BATCH  32
#define K_TOP  128
#define NLAT   (TL * D_SAE)   // 49152
#define NBIN   8192
#define CAP    2048
#define KSPLIT 8
#define KS     (D_IN / KSPLIT)  // 288
#define BK     32
#define NCH    (KS / BK)        // 9

__device__ __forceinline__ void async_cp16(const float* g, float* l) {
    __builtin_amdgcn_global_load_lds(
        (const __attribute__((address_space(1))) unsigned int*)g,
        (__attribute__((address_space(3))) unsigned int*)l, 16, 0, 0);
}

// ---------------- encode: async-staged, double-buffered, vmcnt-counted ----------------
// grid (8, TL, KSPLIT), block 256 (4 waves). Thread owns 1 col, acc over 32 batches.
__global__ __launch_bounds__(256, 2) void enc_kernel(const float* __restrict__ x,
                                                     const float* __restrict__ W,
                                                     float* __restrict__ part) {
    __shared__ float w_s[2][BK][256];     // 64 KB
    __shared__ float x_s[2][BATCH][BK];   // 8 KB

    const int tid  = threadIdx.x;
    const int lane = tid & 63;
    const int wv   = tid >> 6;
    const int tl   = blockIdx.y;
    const int ks   = blockIdx.z;

    const float* Wbase = W + ((size_t)(tl * D_IN + ks * KS)) * D_SAE + blockIdx.x * 256;
    const int xrow  = wv * 8 + (lane >> 3);               // batch row this lane stages
    const float* xbase = x + ((size_t)(xrow * TL + tl)) * D_IN + ks * KS + (lane & 7) * 4;

    // stage chunk ch into buffer nb: 8 W-row loads + 1 x load per wave = 9 vmcnt ops
#define STAGE(nb, ch)                                                          \
    do {                                                                       \
        const float* Wc = Wbase + (size_t)((ch) * BK) * D_SAE;                 \
        _Pragma("unroll")                                                      \
        for (int j = 0; j < 8; ++j) {                                          \
            int r = wv * 8 + j;                                                \
            async_cp16(Wc + (size_t)r * D_SAE + lane * 4, &w_s[nb][r][0]);     \
        }                                                                      \
        async_cp16(xbase + (ch) * BK, &x_s[nb][wv * 8][0]);                    \
    } while (0)

    float acc[BATCH];
#pragma unroll
    for (int b = 0; b < BATCH; b++) acc[b] = 0.f;

    STAGE(0, 0);

    for (int ch = 0; ch < NCH; ++ch) {
        const int cur = ch & 1;
        if (ch + 1 < NCH) {
            STAGE(cur ^ 1, ch + 1);
            asm volatile("s_waitcnt vmcnt(9)" ::: "memory");  // cur chunk's 9 done
        } else {
            asm volatile("s_waitcnt vmcnt(0)" ::: "memory");
        }
        asm volatile("s_barrier" ::: "memory");               // B1: all waves' cur landed

        const float(*ws)[256] = w_s[cur];
        const float(*xs)[BK]  = x_s[cur];
        for (int k0 = 0; k0 < BK; k0 += 4) {
            float w0 = ws[k0][tid], w1 = ws[k0 + 1][tid];
            float w2 = ws[k0 + 2][tid], w3 = ws[k0 + 3][tid];
#pragma unroll
            for (int b = 0; b < BATCH; b++) {
                float4 xv = *(const float4*)&xs[b][k0];       // broadcast
                acc[b] = fmaf(xv.x, w0, acc[b]);
                acc[b] = fmaf(xv.y, w1, acc[b]);
                acc[b] = fmaf(xv.z, w2, acc[b]);
                acc[b] = fmaf(xv.w, w3, acc[b]);
            }
        }
        asm volatile("s_barrier" ::: "memory");               // B2: safe to overwrite
    }
#undef STAGE

    float* pp = part + (size_t)(ks * BATCH) * NLAT + (size_t)tl * D_SAE
              + blockIdx.x * 256 + tid;
#pragma unroll
    for (int b = 0; b < BATCH; b++) pp[(size_t)b * NLAT] = acc[b];
}

// ---------------- reduce partials + bias -> pre ----------------
__global__ void reduce_kernel(const float* __restrict__ part,
                              const float* __restrict__ b_enc,
                              float* __restrict__ pre) {
    int i = blockIdx.x * blockDim.x + threadIdx.x;   // [0, BATCH*NLAT)
    const size_t S = (size_t)BATCH * NLAT;
    float v = 0.f;
#pragma unroll
    for (int s = 0; s < KSPLIT; s++) v += part[i + s * S];
    pre[i] = v + b_enc[i & (D_SAE - 1)];
}

// ---------------- exact top-K per batch row; writes all of z; zeroes loss ----------------
__global__ __launch_bounds__(256) void topk_kernel(const float* __restrict__ pre,
                                                   int* __restrict__ sel_idx,
                                                   float* __restrict__ sel_val,
                                                   float* __restrict__ z,
                                                   float* __restrict__ loss) {
    const int b   = blockIdx.x;
    const int tid = threadIdx.x;
    __shared__ unsigned hist[NBIN];
    __shared__ unsigned cand_key[CAP];
    __shared__ int      cand_idx[CAP];
    __shared__ unsigned tsum[256];
    __shared__ unsigned suf[256];
    __shared__ int s_T, s_hi, s_ccnt, s_sel;

    const float* row  = pre + (size_t)b * NLAT;
    float*       zrow = z   + (size_t)b * NLAT;
    for (int i = tid; i < NBIN; i += 256) hist[i] = 0;
    if (tid == 0) { s_ccnt = 0; s_sel = 0; if (b == 0) *loss = 0.f; }
    __syncthreads();

    for (int i = 4 * tid; i < NLAT; i += 1024) {
        float4 v = *(const float4*)&row[i];
#pragma unroll
        for (int j = 0; j < 4; j++) {
            unsigned u   = __float_as_uint(((const float*)&v)[j]);
            unsigned key = u ^ ((u >> 31) ? 0xFFFFFFFFu : 0x80000000u);
            atomicAdd(&hist[key >> 19], 1u);
        }
    }
    __syncthreads();

    unsigned local = 0;
    const int base = tid * (NBIN / 256);
    for (int j = 0; j < NBIN / 256; j++) local += hist[base + j];
    tsum[tid] = local;
    __syncthreads();
    if (tid == 0) {                 // suffix-exclusive sums over 256 thread ranges
        unsigned run = 0;
        for (int t = 255; t >= 0; t--) { suf[t] = run; run += tsum[t]; }
    }
    __syncthreads();
    if (suf[tid] < K_TOP && suf[tid] + tsum[tid] >= K_TOP) {  // exactly one thread
        unsigned c = suf[tid];
        for (int j = NBIN / 256 - 1; j >= 0; j--) {
            int bin = base + j;
            if (c + hist[bin] >= K_TOP) { s_T = bin; s_hi = (int)c; break; }
            c += hist[bin];
        }
    }
    __syncthreads();

    const int T = s_T;
    for (int i = 4 * tid; i < NLAT; i += 1024) {
        float4 v = *(const float4*)&row[i];
#pragma unroll
        for (int j = 0; j < 4; j++) {
            float f      = ((const float*)&v)[j];
            unsigned u   = __float_as_uint(f);
            unsigned key = u ^ ((u >> 31) ? 0xFFFFFFFFu : 0x80000000u);
            int bin      = (int)(key >> 19);
            float rl     = fmaxf(f, 0.f);
            float zval   = 0.f;
            if (bin > T) {
                int p = atomicAdd(&s_sel, 1);
                sel_idx[b * K_TOP + p] = i + j;
                sel_val[b * K_TOP + p] = rl;
                zval = rl;
            } else if (bin == T) {
                int p = atomicAdd(&s_ccnt, 1);
                if (p < CAP) { cand_key[p] = key; cand_idx[p] = i + j; }
            }
            zrow[i + j] = zval;      // z only 4B-aligned in d_out -> scalar store
        }
    }
    __syncthreads();

    const int need = K_TOP - s_hi;
    const int nc   = min(s_ccnt, CAP);
    for (int c = tid; c < nc; c += 256) {
        unsigned kc = cand_key[c]; int ic = cand_idx[c];
        int rank = 0;
        for (int j = 0; j < nc; j++) {
            unsigned kj = cand_key[j]; int ij = cand_idx[j];
            rank += (kj > kc) || (kj == kc && ij < ic);   // ties -> lower index wins
        }
        if (rank < need) {
            int p = atomicAdd(&s_sel, 1);
            float rl = fmaxf(row[ic], 0.f);
            sel_idx[b * K_TOP + p] = ic;
            sel_val[b * K_TOP + p] = rl;
            zrow[ic] = rl;
        }
    }
}

// ---------------- sparse decode + x_hat + loss ----------------
__global__ __launch_bounds__(256) void dec_kernel(const float* __restrict__ Wd,
                                                  const float* __restrict__ b_dec,
                                                  const float* __restrict__ x,
                                                  const int* __restrict__ sel_idx,
                                                  const float* __restrict__ sel_val,
                                                  float* __restrict__ xhat,
                                                  float* __restrict__ loss) {
    const int tl = blockIdx.x, b = blockIdx.y, tid = threadIdx.x;
    float acc[9];
#pragma unroll
    for (int r = 0; r < 9; r++) acc[r] = b_dec[tl * D_IN + tid + r * 256];

    __shared__ int   s_idx[K_TOP];
    __shared__ float s_val[K_TOP];
    if (tid < K_TOP) { s_idx[tid] = sel_idx[b * K_TOP + tid];
                       s_val[tid] = sel_val[b * K_TOP + tid]; }
    __syncthreads();

    for (int j = 0; j < K_TOP; j++) {
        int f = s_idx[j];
        if ((f >> 11) == tl) {                 // D_SAE = 2048
            float v = s_val[j];
            const float* wrow = Wd + (size_t)f * D_IN;
#pragma unroll
            for (int r = 0; r < 9; r++)
                acc[r] = fmaf(v, wrow[tid + r * 256], acc[r]);
        }
    }

    const float* xr = x    + ((size_t)b * TL + tl) * D_IN;
    float*       xo = xhat + ((size_t)b * TL + tl) * D_IN;
    float lsum = 0.f;
#pragma unroll
    for (int r = 0; r < 9; r++) {
        float d = acc[r] - xr[tid + r * 256];
        xo[tid + r * 256] = acc[r];
        lsum += d * d;
    }
    __shared__ float red[256];
    red[tid] = lsum; __syncthreads();
    for (int s = 128; s > 0; s >>= 1) {
        if (tid < s) red[tid] += red[tid + s];
        __syncthreads();
    }
    if (tid == 0) atomicAdd(loss, red[0] * (1.0f / (BATCH * TL)));
}

extern "C" void kernel_launch(void* const* d_in, const int* in_sizes, int n_in,
                              void* d_out, int out_size, void* d_ws, size_t ws_size,
                              hipStream_t stream) {
    const float* x     = (const float*)d_in[0];
    const float* W_enc = (const float*)d_in[1];
    const float* W_dec = (const float*)d_in[2];
    const float* b_enc = (const float*)d_in[3];
    const float* b_dec = (const float*)d_in[4];

    float* out  = (float*)d_out;
    float* loss = out;
    float* xhat = out + 1;
    float* z    = out + 1 + (size_t)BATCH * TL * D_IN;

    const size_t S = (size_t)BATCH * NLAT;
    float* part    = (float*)d_ws;
    float* pre     = part + (size_t)KSPLIT * S;
    int*   sel_idx = (int*)(pre + S);
    float* sel_val = (float*)(sel_idx + BATCH * K_TOP);

    enc_kernel<<<dim3(8, TL, KSPLIT), 256, 0, stream>>>(x, W_enc, part);
    reduce_kernel<<<(int)(S / 256), 256, 0, stream>>>(part, b_enc, pre);
    topk_kernel<<<BATCH, 256, 0, stream>>>(pre, sel_idx, sel_val, z, loss);
    dec_kernel<<<dim3(TL, BATCH), 256, 0, stream>>>(W_dec, b_dec, x, sel_idx, sel_val,
                                                    xhat, loss);
}

// Round 4
// 196.184 us; speedup vs baseline: 2.8754x; 1.4968x over previous
//
#include <hip/hip_runtime.h>

#define D_IN   2304
#define D_SAE  2048
#define TL     24          // T*L
#define BATCH  32
#define K_TOP  128
#define NLAT   (TL * D_SAE)   // 49152
#define NBIN   8192
#define CAP    2048
#define KSPLIT 4
#define KS     (D_IN / KSPLIT)  // 576
#define BK     16
#define NCH    (KS / BK)        // 36

__device__ __forceinline__ void async_cp16(const float* g, float* l) {
    __builtin_amdgcn_global_load_lds(
        (const __attribute__((address_space(1))) unsigned int*)g,
        (__attribute__((address_space(3))) unsigned int*)l, 16, 0, 0);
}

// ---------------- encode ----------------
// grid (8, TL, KSPLIT), block 256 (4 waves). Thread tile: 8 batches x 4 cols.
// LDS traffic: 48 B per 32 FMA (1.5 B/FMA) -> ~5.4 GB total, ~78 us floor;
// HBM: 453 MB W_enc + partials -> ~82 us floor. 768 blocks = 3/CU, all resident.
__global__ __launch_bounds__(256, 3) void enc_kernel(const float* __restrict__ x,
                                                     const float* __restrict__ W,
                                                     float* __restrict__ part) {
    __shared__ float w_s[2][BK][256];    // 32 KB
    __shared__ float x_s[2][BATCH][BK];  // 4 KB  (flat idx = b*16 + k)

    const int tid  = threadIdx.x;
    const int lane = tid & 63;
    const int wv   = tid >> 6;           // wave id = batch-group = W-row-group
    const int cg   = tid & 63;           // col group (4 consecutive cols)
    const int tl   = blockIdx.y;
    const int ks   = blockIdx.z;

    const float* Wbase = W + ((size_t)(tl * D_IN + ks * KS)) * D_SAE + blockIdx.x * 256;

    // stage chunk ch into buffer buf: 4 W-row gload16 + 2 x gload16 = 6 vm ops/wave.
    // x is staged redundantly by all 4 waves (identical-value writes, benign).
#define STAGE(buf, ch)                                                          \
    do {                                                                        \
        const float* Wc = Wbase + (size_t)((ch) * BK) * D_SAE;                  \
        _Pragma("unroll")                                                       \
        for (int j = 0; j < 4; ++j)                                             \
            async_cp16(Wc + (size_t)(wv * 4 + j) * D_SAE + lane * 4,            \
                       &w_s[buf][wv * 4 + j][0]);                               \
        _Pragma("unroll")                                                       \
        for (int p = 0; p < 2; ++p) {                                           \
            int f = p * 256 + lane * 4;   /* flat float idx into x_s chunk */   \
            int xb = f >> 4, xk = f & 15;                                       \
            async_cp16(x + ((size_t)(xb * TL + tl)) * D_IN + ks * KS            \
                         + (ch) * BK + xk,                                      \
                       &x_s[buf][0][0] + p * 256);                              \
        }                                                                       \
    } while (0)

    float4 acc[8];
#pragma unroll
    for (int j = 0; j < 8; ++j) acc[j] = make_float4(0.f, 0.f, 0.f, 0.f);

    STAGE(0, 0);

    int cur = 0;
    for (int ch = 0; ch < NCH; ++ch) {
        if (ch + 1 < NCH) {
            STAGE(cur ^ 1, ch + 1);                           // next chunk in flight
            asm volatile("s_waitcnt vmcnt(6)" ::: "memory");  // cur chunk's 6 landed
        } else {
            asm volatile("s_waitcnt vmcnt(0)" ::: "memory");
        }
        asm volatile("s_barrier" ::: "memory");               // all waves' cur landed

        const float(*ws)[256] = w_s[cur];
        const float(*xs)[BK]  = x_s[cur];
#pragma unroll
        for (int k = 0; k < BK; ++k) {
            float4 w4 = *(const float4*)&ws[k][cg * 4];
#pragma unroll
            for (int j = 0; j < 8; ++j) {
                float xv = xs[wv * 8 + j][k];                 // broadcast b32
                acc[j].x = fmaf(xv, w4.x, acc[j].x);
                acc[j].y = fmaf(xv, w4.y, acc[j].y);
                acc[j].z = fmaf(xv, w4.z, acc[j].z);
                acc[j].w = fmaf(xv, w4.w, acc[j].w);
            }
        }
        asm volatile("s_barrier" ::: "memory");               // safe to overwrite cur
        cur ^= 1;
    }
#undef STAGE

    float* pp = part + ((size_t)ks * BATCH + wv * 8) * NLAT
              + (size_t)tl * D_SAE + blockIdx.x * 256 + cg * 4;
#pragma unroll
    for (int j = 0; j < 8; ++j)
        *(float4*)&pp[(size_t)j * NLAT] = acc[j];
}

// ---------------- reduce partials + bias -> pre (float4) ----------------
__global__ void reduce_kernel(const float* __restrict__ part,
                              const float* __restrict__ b_enc,
                              float* __restrict__ pre) {
    int i = (blockIdx.x * blockDim.x + threadIdx.x) * 4;   // [0, BATCH*NLAT)
    const size_t S = (size_t)BATCH * NLAT;
    float4 v = *(const float4*)&part[i];
    float4 v1 = *(const float4*)&part[i + S];
    float4 v2 = *(const float4*)&part[i + 2 * S];
    float4 v3 = *(const float4*)&part[i + 3 * S];
    float4 bb = *(const float4*)&b_enc[i & (D_SAE - 1)];
    v.x += v1.x + v2.x + v3.x + bb.x;
    v.y += v1.y + v2.y + v3.y + bb.y;
    v.z += v1.z + v2.z + v3.z + bb.z;
    v.w += v1.w + v2.w + v3.w + bb.w;
    *(float4*)&pre[i] = v;
}

// ---------------- exact top-K per batch row; writes all of z; zeroes loss ----------------
__global__ __launch_bounds__(256) void topk_kernel(const float* __restrict__ pre,
                                                   int* __restrict__ sel_idx,
                                                   float* __restrict__ sel_val,
                                                   float* __restrict__ z,
                                                   float* __restrict__ loss) {
    const int b   = blockIdx.x;
    const int tid = threadIdx.x;
    __shared__ unsigned hist[NBIN];
    __shared__ unsigned cand_key[CAP];
    __shared__ int      cand_idx[CAP];
    __shared__ unsigned tsum[256];
    __shared__ unsigned suf[256];
    __shared__ int s_T, s_hi, s_ccnt, s_sel;

    const float* row  = pre + (size_t)b * NLAT;
    float*       zrow = z   + (size_t)b * NLAT;
    for (int i = tid; i < NBIN; i += 256) hist[i] = 0;
    if (tid == 0) { s_ccnt = 0; s_sel = 0; if (b == 0) *loss = 0.f; }
    __syncthreads();

    for (int i = 4 * tid; i < NLAT; i += 1024) {
        float4 v = *(const float4*)&row[i];
#pragma unroll
        for (int j = 0; j < 4; j++) {
            unsigned u   = __float_as_uint(((const float*)&v)[j]);
            unsigned key = u ^ ((u >> 31) ? 0xFFFFFFFFu : 0x80000000u);
            atomicAdd(&hist[key >> 19], 1u);
        }
    }
    __syncthreads();

    unsigned local = 0;
    const int base = tid * (NBIN / 256);
    for (int j = 0; j < NBIN / 256; j++) local += hist[base + j];
    tsum[tid] = local;
    __syncthreads();
    if (tid == 0) {                 // suffix-exclusive sums over 256 thread ranges
        unsigned run = 0;
        for (int t = 255; t >= 0; t--) { suf[t] = run; run += tsum[t]; }
    }
    __syncthreads();
    if (suf[tid] < K_TOP && suf[tid] + tsum[tid] >= K_TOP) {  // exactly one thread
        unsigned c = suf[tid];
        for (int j = NBIN / 256 - 1; j >= 0; j--) {
            int bin = base + j;
            if (c + hist[bin] >= K_TOP) { s_T = bin; s_hi = (int)c; break; }
            c += hist[bin];
        }
    }
    __syncthreads();

    const int T = s_T;
    for (int i = 4 * tid; i < NLAT; i += 1024) {
        float4 v = *(const float4*)&row[i];
#pragma unroll
        for (int j = 0; j < 4; j++) {
            float f      = ((const float*)&v)[j];
            unsigned u   = __float_as_uint(f);
            unsigned key = u ^ ((u >> 31) ? 0xFFFFFFFFu : 0x80000000u);
            int bin      = (int)(key >> 19);
            float rl     = fmaxf(f, 0.f);
            float zval   = 0.f;
            if (bin > T) {
                int p = atomicAdd(&s_sel, 1);
                sel_idx[b * K_TOP + p] = i + j;
                sel_val[b * K_TOP + p] = rl;
                zval = rl;
            } else if (bin == T) {
                int p = atomicAdd(&s_ccnt, 1);
                if (p < CAP) { cand_key[p] = key; cand_idx[p] = i + j; }
            }
            zrow[i + j] = zval;      // z only 4B-aligned in d_out -> scalar store
        }
    }
    __syncthreads();

    const int need = K_TOP - s_hi;
    const int nc   = min(s_ccnt, CAP);
    for (int c = tid; c < nc; c += 256) {
        unsigned kc = cand_key[c]; int ic = cand_idx[c];
        int rank = 0;
        for (int j = 0; j < nc; j++) {
            unsigned kj = cand_key[j]; int ij = cand_idx[j];
            rank += (kj > kc) || (kj == kc && ij < ic);   // ties -> lower index wins
        }
        if (rank < need) {
            int p = atomicAdd(&s_sel, 1);
            float rl = fmaxf(row[ic], 0.f);
            sel_idx[b * K_TOP + p] = ic;
            sel_val[b * K_TOP + p] = rl;
            zrow[ic] = rl;
        }
    }
}

// ---------------- sparse decode + x_hat + loss ----------------
__global__ __launch_bounds__(256) void dec_kernel(const float* __restrict__ Wd,
                                                  const float* __restrict__ b_dec,
                                                  const float* __restrict__ x,
                                                  const int* __restrict__ sel_idx,
                                                  const float* __restrict__ sel_val,
                                                  float* __restrict__ xhat,
                                                  float* __restrict__ loss) {
    const int tl = blockIdx.x, b = blockIdx.y, tid = threadIdx.x;
    float acc[9];
#pragma unroll
    for (int r = 0; r < 9; r++) acc[r] = b_dec[tl * D_IN + tid + r * 256];

    __shared__ int   s_idx[K_TOP];
    __shared__ float s_val[K_TOP];
    if (tid < K_TOP) { s_idx[tid] = sel_idx[b * K_TOP + tid];
                       s_val[tid] = sel_val[b * K_TOP + tid]; }
    __syncthreads();

    for (int j = 0; j < K_TOP; j++) {
        int f = s_idx[j];
        if ((f >> 11) == tl) {                 // D_SAE = 2048
            float v = s_val[j];
            const float* wrow = Wd + (size_t)f * D_IN;
#pragma unroll
            for (int r = 0; r < 9; r++)
                acc[r] = fmaf(v, wrow[tid + r * 256], acc[r]);
        }
    }

    const float* xr = x    + ((size_t)b * TL + tl) * D_IN;
    float*       xo = xhat + ((size_t)b * TL + tl) * D_IN;
    float lsum = 0.f;
#pragma unroll
    for (int r = 0; r < 9; r++) {
        float d = acc[r] - xr[tid + r * 256];
        xo[tid + r * 256] = acc[r];
        lsum += d * d;
    }
    __shared__ float red[256];
    red[tid] = lsum; __syncthreads();
    for (int s = 128; s > 0; s >>= 1) {
        if (tid < s) red[tid] += red[tid + s];
        __syncthreads();
    }
    if (tid == 0) atomicAdd(loss, red[0] * (1.0f / (BATCH * TL)));
}

extern "C" void kernel_launch(void* const* d_in, const int* in_sizes, int n_in,
                              void* d_out, int out_size, void* d_ws, size_t ws_size,
                              hipStream_t stream) {
    const float* x     = (const float*)d_in[0];
    const float* W_enc = (const float*)d_in[1];
    const float* W_dec = (const float*)d_in[2];
    const float* b_enc = (const float*)d_in[3];
    const float* b_dec = (const float*)d_in[4];

    float* out  = (float*)d_out;
    float* loss = out;
    float* xhat = out + 1;
    float* z    = out + 1 + (size_t)BATCH * TL * D_IN;

    const size_t S = (size_t)BATCH * NLAT;
    float* part    = (float*)d_ws;
    float* pre     = part + (size_t)KSPLIT * S;
    int*   sel_idx = (int*)(pre + S);
    float* sel_val = (float*)(sel_idx + BATCH * K_TOP);

    enc_kernel<<<dim3(8, TL, KSPLIT), 256, 0, stream>>>(x, W_enc, part);
    reduce_kernel<<<(int)(S / 1024), 256, 0, stream>>>(part, b_enc, pre);
    topk_kernel<<<BATCH, 256, 0, stream>>>(pre, sel_idx, sel_val, z, loss);
    dec_kernel<<<dim3(TL, BATCH), 256, 0, stream>>>(W_dec, b_dec, x, sel_idx, sel_val,
                                                    xhat, loss);
}